// Round 10
// baseline (22.441 us; speedup 1.0000x reference)
//
#include <hip/hip_runtime.h>
#include <math.h>

#define B 32
#define C 4
#define CF 5
#define WPB 8           // waves per block; wave wv handles l = blk*8 + wv
#define NTHR (WPB * 64) // 512

// Tiny counter-zeroing kernel: replaces hipMemsetAsync, whose runtime fill
// dispatch measured ~5-8us in-graph (R7 profile: 39us fillBufferAligned for
// a 4-byte write).
__global__ void k_zero(unsigned* counter) {
    __hip_atomic_store(counter, 0u, __ATOMIC_RELAXED, __HIP_MEMORY_SCOPE_AGENT);
}

// Fused main kernel: staging waves 0-3 (one (b,l) record/thread, coalesced),
// w-table waves 4-7, per-wave all-pairs JS via 8 shfl rotation steps with
// ballot same-label masks; fence-free agent-scope tail (sc1) does the final
// reduction in the last-finishing block. NO __threadfence (device fence =
// L2 writeback across 8 XCDs = ~75us, measured R6).
__global__ __launch_bounds__(NTHR) void k_main(const float* __restrict__ logits,
                                               const float* __restrict__ prob,
                                               const float* __restrict__ y_true,
                                               const float* __restrict__ yevo,
                                               float* __restrict__ partials,
                                               unsigned* __restrict__ counter,
                                               float* __restrict__ out,
                                               int L, int nblk) {
    const int t = threadIdx.x;
    const int blk = blockIdx.x;
    const int l0 = blk << 3;

    __shared__ float w[1024];                   // evo weight matrix
    __shared__ float sq0[WPB][33], sq1[WPB][33], sq2[WPB][33], sq3[WPB][33];
    __shared__ float smp[WPB][33];              // sum p*log p
    __shared__ int   sl[WPB][33];               // labels
    __shared__ float wred[WPB][5];
    __shared__ unsigned done_s;

    float ce = 0.f, valid = 0.f, r2s = 0.f, tv = 0.f;

    if (t < 256) {
        // ---- one (b, l) record per thread (waves 0-3); consecutive t ->
        //      consecutive l => contiguous global segments ----
        const int b = t >> 3, ll = t & 7;
        const int l = l0 + ll;
        const float* yt = y_true + ((size_t)b * L + l) * CF;
        float y0 = yt[0], y1 = yt[1], y2 = yt[2], y3 = yt[3], y4 = yt[4];
        float4 pv = *(const float4*)(prob + ((size_t)b * L + l) * C);
        float4 av = *(const float4*)(logits + ((size_t)b * L + l) * C);

        int lbl = 0; float best = y0;
        if (y1 > best) { best = y1; lbl = 1; }
        if (y2 > best) { best = y2; lbl = 2; }
        if (y3 > best) { best = y3; lbl = 3; }
        if (y4 > best) { best = y4; lbl = 4; }
        float salt = y1 + y2 + y3;

        float spalt = pv.y + pv.z + pv.w;       // raw probs per reference
        float q0 = fmaxf(pv.x, 1e-7f), q1 = fmaxf(pv.y, 1e-7f);
        float q2 = fmaxf(pv.z, 1e-7f), q3 = fmaxf(pv.w, 1e-7f);
        float plp = q0 * __logf(q0) + q1 * __logf(q1)
                  + q2 * __logf(q2) + q3 * __logf(q3);

        sq0[ll][b] = q0; sq1[ll][b] = q1; sq2[ll][b] = q2; sq3[ll][b] = q3;
        smp[ll][b] = plp; sl[ll][b] = lbl;

        if (lbl != 4) {                         // CE (ignore_index = 4)
            float mx = fmaxf(fmaxf(av.x, av.y), fmaxf(av.z, av.w));
            float se = __expf(av.x - mx) + __expf(av.y - mx)
                     + __expf(av.z - mx) + __expf(av.w - mx);
            float lse = mx + __logf(se);
            float al = (lbl == 0) ? av.x : (lbl == 1) ? av.y
                     : (lbl == 2) ? av.z : av.w;
            ce = lse - al;
            valid = 1.f;
        }

        // R2: group of 4 = b bits 0,1 = t bits 3,4 (in-wave)
        float nmc = (lbl != 4) ? 1.f : 0.f, altc = salt, ps = spalt;
        nmc  += __shfl_xor(nmc, 8);   nmc  += __shfl_xor(nmc, 16);
        altc += __shfl_xor(altc, 8);  altc += __shfl_xor(altc, 16);
        ps   += __shfl_xor(ps, 8);    ps   += __shfl_xor(ps, 16);
        float af = altc / fmaxf(nmc, 1.f);
        float pred = 0.25f * ps;
        bool miss = (lbl == 4);
        float taf = miss ? 0.5f : af;
        bool edge = (taf == 0.f) || (taf == 1.f);
        float denom = fmaxf(taf * (1.f - taf), 0.01f);
        float d = pred - taf;
        float r2 = d * d / denom;
        if (edge || miss) r2 = 0.f;
        r2s -= r2;
        if (nmc > 0.f && r2 != 0.f) tv += 1.f;
    } else {
        // ---- w-table (waves 4-7): row i, 4 cols per thread ----
        int t2 = t - 256;
        int i = t2 >> 3, j4 = (t2 & 7) << 2;
        float4 ye = *(const float4*)(yevo + (i << 5) + j4);
        float e0 = __expf(-2.f * ye.x), e1 = __expf(-2.f * ye.y);
        float e2 = __expf(-2.f * ye.z), e3 = __expf(-2.f * ye.w);
        float s = e0 + e1 + e2 + e3;
        s += __shfl_xor(s, 1);
        s += __shfl_xor(s, 2);
        s += __shfl_xor(s, 4);                  // rowsum over 8 lanes
        float inv = 1.f / (s + 1e-8f);
        *(float4*)&w[(i << 5) + j4] =
            make_float4(e0 * inv, e1 * inv, e2 * inv, e3 * inv);
    }
    __syncthreads();

    // ---- pair phase: wave wv <-> l = l0+wv ----
    const int lane = t & 63;
    const int g = lane >> 5;                    // 0: d=1..8, 1: d=9..16
    const int b = lane & 31;                    // owned batch row
    const int wv = t >> 6;

    float q0 = sq0[wv][b], q1 = sq1[wv][b], q2 = sq2[wv][b], q3 = sq3[wv][b];
    float plp = smp[wv][b];
    int   lbl = sl[wv][b];

    // ballot-precomputed same-label mask (rows 0-31 in low bits; both wave
    // halves hold identical row labels, so low 32 bits are valid)
    unsigned long long bm0 = __ballot(lbl == 0);
    unsigned long long bm1 = __ballot(lbl == 1);
    unsigned long long bm2 = __ballot(lbl == 2);
    unsigned long long bm3 = __ballot(lbl == 3);
    unsigned mask = (unsigned)(lbl == 0 ? bm0 : lbl == 1 ? bm1
                             : lbl == 2 ? bm2 : lbl == 3 ? bm3 : 0ull);

    float evo = 0.f;
    #pragma unroll
    for (int it = 0; it < 8; ++it) {
        int d = 1 + it + (g << 3);
        int jj = (b + d) & 31;
        int src = (lane & 32) | jj;
        float qj0 = __shfl(q0, src), qj1 = __shfl(q1, src);
        float qj2 = __shfl(q2, src), qj3 = __shfl(q3, src);
        float pj  = __shfl(plp, src);
        float m0 = 0.5f * (q0 + qj0), m1 = 0.5f * (q1 + qj1);
        float m2 = 0.5f * (q2 + qj2), m3 = 0.5f * (q3 + qj3);
        float mlogm = m0 * __logf(m0) + m1 * __logf(m1)
                    + m2 * __logf(m2) + m3 * __logf(m3);
        float js = 0.5f * (plp + pj) - mlogm;
        bool act = ((mask >> jj) & 1u) && !((d == 16) && (b >= 16));
        float wf = act ? (w[(b << 5) + jj] + w[(jj << 5) + b]) : 0.f;
        evo = fmaf(wf, js, evo);
    }

    // ---- wave reduction of 5 accumulators ----
    #pragma unroll
    for (int off = 32; off; off >>= 1) {
        ce += __shfl_xor(ce, off);   valid += __shfl_xor(valid, off);
        r2s += __shfl_xor(r2s, off); tv += __shfl_xor(tv, off);
        evo += __shfl_xor(evo, off);
    }
    if (lane == 0) {
        wred[wv][0] = ce; wred[wv][1] = valid; wred[wv][2] = r2s;
        wred[wv][3] = tv; wred[wv][4] = evo;
    }
    __syncthreads();

    // ---- cross-wave reduction (8 waves) + agent-scope publish ----
    if (t < 8) {
        float a0 = wred[t][0], a1 = wred[t][1], a2 = wred[t][2],
              a3 = wred[t][3], a4 = wred[t][4];
        #pragma unroll
        for (int off = 4; off; off >>= 1) {
            a0 += __shfl_xor(a0, off); a1 += __shfl_xor(a1, off);
            a2 += __shfl_xor(a2, off); a3 += __shfl_xor(a3, off);
            a4 += __shfl_xor(a4, off);
        }
        if (t == 0) {
            // agent-scope coherent stores (sc1): device-visible without any
            // L2 writeback instruction. [5][nblk] layout for coalesced tail.
            __hip_atomic_store(&partials[0 * nblk + blk], a0, __ATOMIC_RELAXED, __HIP_MEMORY_SCOPE_AGENT);
            __hip_atomic_store(&partials[1 * nblk + blk], a1, __ATOMIC_RELAXED, __HIP_MEMORY_SCOPE_AGENT);
            __hip_atomic_store(&partials[2 * nblk + blk], a2, __ATOMIC_RELAXED, __HIP_MEMORY_SCOPE_AGENT);
            __hip_atomic_store(&partials[3 * nblk + blk], a3, __ATOMIC_RELAXED, __HIP_MEMORY_SCOPE_AGENT);
            __hip_atomic_store(&partials[4 * nblk + blk], a4, __ATOMIC_RELAXED, __HIP_MEMORY_SCOPE_AGENT);
            asm volatile("s_waitcnt vmcnt(0)" ::: "memory");
            done_s = __hip_atomic_fetch_add(counter, 1u, __ATOMIC_RELAXED,
                                            __HIP_MEMORY_SCOPE_AGENT);
        }
    }
    __syncthreads();
    if (done_s != (unsigned)(nblk - 1)) return;

    // ---- last block: final reduction + epilogue (agent-scope loads) ----
    float s0 = 0.f, s1 = 0.f, s2 = 0.f, s3 = 0.f, s4 = 0.f;
    {   // nblk == NTHR == 512: one block-partial per thread, coalesced
        s0 = __hip_atomic_load(&partials[0 * nblk + t], __ATOMIC_RELAXED, __HIP_MEMORY_SCOPE_AGENT);
        s1 = __hip_atomic_load(&partials[1 * nblk + t], __ATOMIC_RELAXED, __HIP_MEMORY_SCOPE_AGENT);
        s2 = __hip_atomic_load(&partials[2 * nblk + t], __ATOMIC_RELAXED, __HIP_MEMORY_SCOPE_AGENT);
        s3 = __hip_atomic_load(&partials[3 * nblk + t], __ATOMIC_RELAXED, __HIP_MEMORY_SCOPE_AGENT);
        s4 = __hip_atomic_load(&partials[4 * nblk + t], __ATOMIC_RELAXED, __HIP_MEMORY_SCOPE_AGENT);
    }
    #pragma unroll
    for (int off = 32; off; off >>= 1) {
        s0 += __shfl_xor(s0, off); s1 += __shfl_xor(s1, off);
        s2 += __shfl_xor(s2, off); s3 += __shfl_xor(s3, off);
        s4 += __shfl_xor(s4, off);
    }
    if (lane == 0) {
        wred[wv][0] = s0; wred[wv][1] = s1; wred[wv][2] = s2;
        wred[wv][3] = s3; wred[wv][4] = s4;
    }
    __syncthreads();
    if (t == 0) {
        float ce_sum = 0.f, vcnt = 0.f, r2_sum = 0.f, tvs = 0.f, evo_s = 0.f;
        #pragma unroll
        for (int k = 0; k < WPB; ++k) {
            ce_sum += wred[k][0]; vcnt += wred[k][1]; r2_sum += wred[k][2];
            tvs += wred[k][3]; evo_s += wred[k][4];
        }
        float ce_loss = (vcnt > 0.f) ? (ce_sum / fmaxf(vcnt, 1.f)) : ce_sum;
        float r2_loss = 0.1f * ((tvs > 0.f) ? (r2_sum / fmaxf(tvs, 1.f)) : r2_sum);
        float evo = 10.f * (evo_s / 32.f);
        if (!isfinite(evo)) evo = 0.f;
        out[0] = 1000.f * (ce_loss + r2_loss + evo);
    }
}

extern "C" void kernel_launch(void* const* d_in, const int* in_sizes, int n_in,
                              void* d_out, int out_size, void* d_ws, size_t ws_size,
                              hipStream_t stream) {
    const float* logits = (const float*)d_in[0];
    const float* prob   = (const float*)d_in[1];
    const float* y_true = (const float*)d_in[2];
    const float* yevo   = (const float*)d_in[3];
    float* out = (float*)d_out;

    const int L = in_sizes[0] / (B * C);   // 4096
    const int nblk = L / WPB;              // 512

    float* partials   = (float*)d_ws;                       // 5*nblk floats
    unsigned* counter = (unsigned*)((float*)d_ws + 5 * nblk);

    k_zero<<<1, 1, 0, stream>>>(counter);
    k_main<<<nblk, NTHR, 0, stream>>>(logits, prob, y_true, yevo,
                                      partials, counter, out, L, nblk);
}

// Round 11
// 16.601 us; speedup vs baseline: 1.3518x; 1.3518x over previous
//
#include <hip/hip_runtime.h>
#include <math.h>

#define B 32
#define C 4
#define CF 5
#define WPB 8           // waves per block; wave wv handles l = blk*8 + wv
#define NTHR (WPB * 64) // 512

// k_main: staging waves 0-3 (one (b,l) record/thread, coalesced),
// w-table waves 4-7 (float4), then per-wave all-pairs JS via 8 shfl
// rotation steps with ballot-precomputed same-label masks.
// (R8 champion, verbatim — 14.7us total in the two-kernel shape.)
__global__ __launch_bounds__(NTHR) void k_main(const float* __restrict__ logits,
                                               const float* __restrict__ prob,
                                               const float* __restrict__ y_true,
                                               const float* __restrict__ yevo,
                                               float* __restrict__ partials,
                                               int L, int nblk) {
    const int t = threadIdx.x;
    const int blk = blockIdx.x;
    const int l0 = blk << 3;

    __shared__ float w[1024];                   // evo weight matrix
    __shared__ float sq0[WPB][33], sq1[WPB][33], sq2[WPB][33], sq3[WPB][33];
    __shared__ float smp[WPB][33];              // sum p*log p
    __shared__ int   sl[WPB][33];               // labels
    __shared__ float wred[WPB][5];

    float ce = 0.f, valid = 0.f, r2s = 0.f, tv = 0.f;

    if (t < 256) {
        // ---- one (b, l) record per thread (waves 0-3); consecutive t ->
        //      consecutive l => contiguous global segments ----
        const int b = t >> 3, ll = t & 7;
        const int l = l0 + ll;
        const float* yt = y_true + ((size_t)b * L + l) * CF;
        float y0 = yt[0], y1 = yt[1], y2 = yt[2], y3 = yt[3], y4 = yt[4];
        float4 pv = *(const float4*)(prob + ((size_t)b * L + l) * C);
        float4 av = *(const float4*)(logits + ((size_t)b * L + l) * C);

        int lbl = 0; float best = y0;
        if (y1 > best) { best = y1; lbl = 1; }
        if (y2 > best) { best = y2; lbl = 2; }
        if (y3 > best) { best = y3; lbl = 3; }
        if (y4 > best) { best = y4; lbl = 4; }
        float salt = y1 + y2 + y3;

        float spalt = pv.y + pv.z + pv.w;       // raw probs per reference
        float q0 = fmaxf(pv.x, 1e-7f), q1 = fmaxf(pv.y, 1e-7f);
        float q2 = fmaxf(pv.z, 1e-7f), q3 = fmaxf(pv.w, 1e-7f);
        float plp = q0 * __logf(q0) + q1 * __logf(q1)
                  + q2 * __logf(q2) + q3 * __logf(q3);

        sq0[ll][b] = q0; sq1[ll][b] = q1; sq2[ll][b] = q2; sq3[ll][b] = q3;
        smp[ll][b] = plp; sl[ll][b] = lbl;

        if (lbl != 4) {                         // CE (ignore_index = 4)
            float mx = fmaxf(fmaxf(av.x, av.y), fmaxf(av.z, av.w));
            float se = __expf(av.x - mx) + __expf(av.y - mx)
                     + __expf(av.z - mx) + __expf(av.w - mx);
            float lse = mx + __logf(se);
            float al = (lbl == 0) ? av.x : (lbl == 1) ? av.y
                     : (lbl == 2) ? av.z : av.w;
            ce = lse - al;
            valid = 1.f;
        }

        // R2: group of 4 = b bits 0,1 = t bits 3,4 (in-wave)
        float nmc = (lbl != 4) ? 1.f : 0.f, altc = salt, ps = spalt;
        nmc  += __shfl_xor(nmc, 8);   nmc  += __shfl_xor(nmc, 16);
        altc += __shfl_xor(altc, 8);  altc += __shfl_xor(altc, 16);
        ps   += __shfl_xor(ps, 8);    ps   += __shfl_xor(ps, 16);
        float af = altc / fmaxf(nmc, 1.f);
        float pred = 0.25f * ps;
        bool miss = (lbl == 4);
        float taf = miss ? 0.5f : af;
        bool edge = (taf == 0.f) || (taf == 1.f);
        float denom = fmaxf(taf * (1.f - taf), 0.01f);
        float d = pred - taf;
        float r2 = d * d / denom;
        if (edge || miss) r2 = 0.f;
        r2s -= r2;
        if (nmc > 0.f && r2 != 0.f) tv += 1.f;
    } else {
        // ---- w-table (waves 4-7): row i, 4 cols per thread ----
        int t2 = t - 256;
        int i = t2 >> 3, j4 = (t2 & 7) << 2;
        float4 ye = *(const float4*)(yevo + (i << 5) + j4);
        float e0 = __expf(-2.f * ye.x), e1 = __expf(-2.f * ye.y);
        float e2 = __expf(-2.f * ye.z), e3 = __expf(-2.f * ye.w);
        float s = e0 + e1 + e2 + e3;
        s += __shfl_xor(s, 1);
        s += __shfl_xor(s, 2);
        s += __shfl_xor(s, 4);                  // rowsum over 8 lanes
        float inv = 1.f / (s + 1e-8f);
        *(float4*)&w[(i << 5) + j4] =
            make_float4(e0 * inv, e1 * inv, e2 * inv, e3 * inv);
    }
    __syncthreads();

    // ---- pair phase: wave wv <-> l = l0+wv ----
    const int lane = t & 63;
    const int g = lane >> 5;                    // 0: d=1..8, 1: d=9..16
    const int b = lane & 31;                    // owned batch row
    const int wv = t >> 6;

    float q0 = sq0[wv][b], q1 = sq1[wv][b], q2 = sq2[wv][b], q3 = sq3[wv][b];
    float plp = smp[wv][b];
    int   lbl = sl[wv][b];

    // ballot-precomputed same-label mask (rows 0-31 in low bits; both wave
    // halves hold identical row labels, so low 32 bits are valid)
    unsigned long long bm0 = __ballot(lbl == 0);
    unsigned long long bm1 = __ballot(lbl == 1);
    unsigned long long bm2 = __ballot(lbl == 2);
    unsigned long long bm3 = __ballot(lbl == 3);
    unsigned mask = (unsigned)(lbl == 0 ? bm0 : lbl == 1 ? bm1
                             : lbl == 2 ? bm2 : lbl == 3 ? bm3 : 0ull);

    float evo = 0.f;
    #pragma unroll
    for (int it = 0; it < 8; ++it) {
        int d = 1 + it + (g << 3);
        int jj = (b + d) & 31;
        int src = (lane & 32) | jj;
        float qj0 = __shfl(q0, src), qj1 = __shfl(q1, src);
        float qj2 = __shfl(q2, src), qj3 = __shfl(q3, src);
        float pj  = __shfl(plp, src);
        float m0 = 0.5f * (q0 + qj0), m1 = 0.5f * (q1 + qj1);
        float m2 = 0.5f * (q2 + qj2), m3 = 0.5f * (q3 + qj3);
        float mlogm = m0 * __logf(m0) + m1 * __logf(m1)
                    + m2 * __logf(m2) + m3 * __logf(m3);
        float js = 0.5f * (plp + pj) - mlogm;
        bool act = ((mask >> jj) & 1u) && !((d == 16) && (b >= 16));
        float wf = act ? (w[(b << 5) + jj] + w[(jj << 5) + b]) : 0.f;
        evo = fmaf(wf, js, evo);
    }

    // ---- wave reduction of 5 accumulators ----
    #pragma unroll
    for (int off = 32; off; off >>= 1) {
        ce += __shfl_xor(ce, off);   valid += __shfl_xor(valid, off);
        r2s += __shfl_xor(r2s, off); tv += __shfl_xor(tv, off);
        evo += __shfl_xor(evo, off);
    }
    if (lane == 0) {
        wred[wv][0] = ce; wred[wv][1] = valid; wred[wv][2] = r2s;
        wred[wv][3] = tv; wred[wv][4] = evo;
    }
    __syncthreads();

    // ---- cross-wave reduction (8 waves) by wave 0, lanes 0..7 ----
    if (t < 8) {
        float a0 = wred[t][0], a1 = wred[t][1], a2 = wred[t][2],
              a3 = wred[t][3], a4 = wred[t][4];
        #pragma unroll
        for (int off = 4; off; off >>= 1) {
            a0 += __shfl_xor(a0, off); a1 += __shfl_xor(a1, off);
            a2 += __shfl_xor(a2, off); a3 += __shfl_xor(a3, off);
            a4 += __shfl_xor(a4, off);
        }
        if (t == 0) {                   // [5][nblk] layout: k_final coalesced
            partials[0 * nblk + blk] = a0;
            partials[1 * nblk + blk] = a1;
            partials[2 * nblk + blk] = a2;
            partials[3 * nblk + blk] = a3;
            partials[4 * nblk + blk] = a4;
        }
    }
}

// Slim epilogue: ONE 64-lane wave, pure shfl reduction — no LDS, no
// __syncthreads, minimal ramp. nblk = 512 -> 8 strided coalesced loads
// per accumulator per lane.
__global__ __launch_bounds__(64) void k_final(const float* __restrict__ partials,
                                              float* __restrict__ out, int nblk) {
    const int lane = threadIdx.x;
    float s0 = 0.f, s1 = 0.f, s2 = 0.f, s3 = 0.f, s4 = 0.f;
    for (int idx = lane; idx < nblk; idx += 64) {
        s0 += partials[0 * nblk + idx];
        s1 += partials[1 * nblk + idx];
        s2 += partials[2 * nblk + idx];
        s3 += partials[3 * nblk + idx];
        s4 += partials[4 * nblk + idx];
    }
    #pragma unroll
    for (int off = 32; off; off >>= 1) {
        s0 += __shfl_xor(s0, off); s1 += __shfl_xor(s1, off);
        s2 += __shfl_xor(s2, off); s3 += __shfl_xor(s3, off);
        s4 += __shfl_xor(s4, off);
    }
    if (lane == 0) {
        float ce_loss = (s1 > 0.f) ? (s0 / fmaxf(s1, 1.f)) : s0;
        float r2_loss = 0.1f * ((s3 > 0.f) ? (s2 / fmaxf(s3, 1.f)) : s2);
        float evo = 10.f * (s4 / 32.f);
        if (!isfinite(evo)) evo = 0.f;
        out[0] = 1000.f * (ce_loss + r2_loss + evo);
    }
}

extern "C" void kernel_launch(void* const* d_in, const int* in_sizes, int n_in,
                              void* d_out, int out_size, void* d_ws, size_t ws_size,
                              hipStream_t stream) {
    const float* logits = (const float*)d_in[0];
    const float* prob   = (const float*)d_in[1];
    const float* y_true = (const float*)d_in[2];
    const float* yevo   = (const float*)d_in[3];
    float* out = (float*)d_out;

    const int L = in_sizes[0] / (B * C);   // 4096
    const int nblk = L / WPB;              // 512

    float* partials = (float*)d_ws;        // 5 * nblk floats

    k_main<<<nblk, NTHR, 0, stream>>>(logits, prob, y_true, yevo,
                                      partials, L, nblk);
    k_final<<<1, 64, 0, stream>>>(partials, out, nblk);
}

// Round 12
// 14.787 us; speedup vs baseline: 1.5176x; 1.1227x over previous
//
#include <hip/hip_runtime.h>
#include <math.h>

#define B 32
#define C 4
#define CF 5
#define WPB 8           // waves per block; wave wv handles l = blk*8 + wv
#define NTHR (WPB * 64) // 512

// k_main: staging waves 0-3 (one (b,l) record/thread, coalesced),
// w-table waves 4-7 (float4), then per-wave all-pairs JS via 8 shfl
// rotation steps with ballot-precomputed same-label masks.
// (R8 champion, verbatim — 14.7us total in the two-kernel shape.)
__global__ __launch_bounds__(NTHR) void k_main(const float* __restrict__ logits,
                                               const float* __restrict__ prob,
                                               const float* __restrict__ y_true,
                                               const float* __restrict__ yevo,
                                               float* __restrict__ partials,
                                               int L, int nblk) {
    const int t = threadIdx.x;
    const int blk = blockIdx.x;
    const int l0 = blk << 3;

    __shared__ float w[1024];                   // evo weight matrix
    __shared__ float sq0[WPB][33], sq1[WPB][33], sq2[WPB][33], sq3[WPB][33];
    __shared__ float smp[WPB][33];              // sum p*log p
    __shared__ int   sl[WPB][33];               // labels
    __shared__ float wred[WPB][5];

    float ce = 0.f, valid = 0.f, r2s = 0.f, tv = 0.f;

    if (t < 256) {
        // ---- one (b, l) record per thread (waves 0-3); consecutive t ->
        //      consecutive l => contiguous global segments ----
        const int b = t >> 3, ll = t & 7;
        const int l = l0 + ll;
        const float* yt = y_true + ((size_t)b * L + l) * CF;
        float y0 = yt[0], y1 = yt[1], y2 = yt[2], y3 = yt[3], y4 = yt[4];
        float4 pv = *(const float4*)(prob + ((size_t)b * L + l) * C);
        float4 av = *(const float4*)(logits + ((size_t)b * L + l) * C);

        int lbl = 0; float best = y0;
        if (y1 > best) { best = y1; lbl = 1; }
        if (y2 > best) { best = y2; lbl = 2; }
        if (y3 > best) { best = y3; lbl = 3; }
        if (y4 > best) { best = y4; lbl = 4; }
        float salt = y1 + y2 + y3;

        float spalt = pv.y + pv.z + pv.w;       // raw probs per reference
        float q0 = fmaxf(pv.x, 1e-7f), q1 = fmaxf(pv.y, 1e-7f);
        float q2 = fmaxf(pv.z, 1e-7f), q3 = fmaxf(pv.w, 1e-7f);
        float plp = q0 * __logf(q0) + q1 * __logf(q1)
                  + q2 * __logf(q2) + q3 * __logf(q3);

        sq0[ll][b] = q0; sq1[ll][b] = q1; sq2[ll][b] = q2; sq3[ll][b] = q3;
        smp[ll][b] = plp; sl[ll][b] = lbl;

        if (lbl != 4) {                         // CE (ignore_index = 4)
            float mx = fmaxf(fmaxf(av.x, av.y), fmaxf(av.z, av.w));
            float se = __expf(av.x - mx) + __expf(av.y - mx)
                     + __expf(av.z - mx) + __expf(av.w - mx);
            float lse = mx + __logf(se);
            float al = (lbl == 0) ? av.x : (lbl == 1) ? av.y
                     : (lbl == 2) ? av.z : av.w;
            ce = lse - al;
            valid = 1.f;
        }

        // R2: group of 4 = b bits 0,1 = t bits 3,4 (in-wave)
        float nmc = (lbl != 4) ? 1.f : 0.f, altc = salt, ps = spalt;
        nmc  += __shfl_xor(nmc, 8);   nmc  += __shfl_xor(nmc, 16);
        altc += __shfl_xor(altc, 8);  altc += __shfl_xor(altc, 16);
        ps   += __shfl_xor(ps, 8);    ps   += __shfl_xor(ps, 16);
        float af = altc / fmaxf(nmc, 1.f);
        float pred = 0.25f * ps;
        bool miss = (lbl == 4);
        float taf = miss ? 0.5f : af;
        bool edge = (taf == 0.f) || (taf == 1.f);
        float denom = fmaxf(taf * (1.f - taf), 0.01f);
        float d = pred - taf;
        float r2 = d * d / denom;
        if (edge || miss) r2 = 0.f;
        r2s -= r2;
        if (nmc > 0.f && r2 != 0.f) tv += 1.f;
    } else {
        // ---- w-table (waves 4-7): row i, 4 cols per thread ----
        int t2 = t - 256;
        int i = t2 >> 3, j4 = (t2 & 7) << 2;
        float4 ye = *(const float4*)(yevo + (i << 5) + j4);
        float e0 = __expf(-2.f * ye.x), e1 = __expf(-2.f * ye.y);
        float e2 = __expf(-2.f * ye.z), e3 = __expf(-2.f * ye.w);
        float s = e0 + e1 + e2 + e3;
        s += __shfl_xor(s, 1);
        s += __shfl_xor(s, 2);
        s += __shfl_xor(s, 4);                  // rowsum over 8 lanes
        float inv = 1.f / (s + 1e-8f);
        *(float4*)&w[(i << 5) + j4] =
            make_float4(e0 * inv, e1 * inv, e2 * inv, e3 * inv);
    }
    __syncthreads();

    // ---- pair phase: wave wv <-> l = l0+wv ----
    const int lane = t & 63;
    const int g = lane >> 5;                    // 0: d=1..8, 1: d=9..16
    const int b = lane & 31;                    // owned batch row
    const int wv = t >> 6;

    float q0 = sq0[wv][b], q1 = sq1[wv][b], q2 = sq2[wv][b], q3 = sq3[wv][b];
    float plp = smp[wv][b];
    int   lbl = sl[wv][b];

    // ballot-precomputed same-label mask (rows 0-31 in low bits; both wave
    // halves hold identical row labels, so low 32 bits are valid)
    unsigned long long bm0 = __ballot(lbl == 0);
    unsigned long long bm1 = __ballot(lbl == 1);
    unsigned long long bm2 = __ballot(lbl == 2);
    unsigned long long bm3 = __ballot(lbl == 3);
    unsigned mask = (unsigned)(lbl == 0 ? bm0 : lbl == 1 ? bm1
                             : lbl == 2 ? bm2 : lbl == 3 ? bm3 : 0ull);

    float evo = 0.f;
    #pragma unroll
    for (int it = 0; it < 8; ++it) {
        int d = 1 + it + (g << 3);
        int jj = (b + d) & 31;
        int src = (lane & 32) | jj;
        float qj0 = __shfl(q0, src), qj1 = __shfl(q1, src);
        float qj2 = __shfl(q2, src), qj3 = __shfl(q3, src);
        float pj  = __shfl(plp, src);
        float m0 = 0.5f * (q0 + qj0), m1 = 0.5f * (q1 + qj1);
        float m2 = 0.5f * (q2 + qj2), m3 = 0.5f * (q3 + qj3);
        float mlogm = m0 * __logf(m0) + m1 * __logf(m1)
                    + m2 * __logf(m2) + m3 * __logf(m3);
        float js = 0.5f * (plp + pj) - mlogm;
        bool act = ((mask >> jj) & 1u) && !((d == 16) && (b >= 16));
        float wf = act ? (w[(b << 5) + jj] + w[(jj << 5) + b]) : 0.f;
        evo = fmaf(wf, js, evo);
    }

    // ---- wave reduction of 5 accumulators ----
    #pragma unroll
    for (int off = 32; off; off >>= 1) {
        ce += __shfl_xor(ce, off);   valid += __shfl_xor(valid, off);
        r2s += __shfl_xor(r2s, off); tv += __shfl_xor(tv, off);
        evo += __shfl_xor(evo, off);
    }
    if (lane == 0) {
        wred[wv][0] = ce; wred[wv][1] = valid; wred[wv][2] = r2s;
        wred[wv][3] = tv; wred[wv][4] = evo;
    }
    __syncthreads();

    // ---- cross-wave reduction (8 waves) by wave 0, lanes 0..7 ----
    if (t < 8) {
        float a0 = wred[t][0], a1 = wred[t][1], a2 = wred[t][2],
              a3 = wred[t][3], a4 = wred[t][4];
        #pragma unroll
        for (int off = 4; off; off >>= 1) {
            a0 += __shfl_xor(a0, off); a1 += __shfl_xor(a1, off);
            a2 += __shfl_xor(a2, off); a3 += __shfl_xor(a3, off);
            a4 += __shfl_xor(a4, off);
        }
        if (t == 0) {                   // [5][nblk] layout: k_final coalesced
            partials[0 * nblk + blk] = a0;
            partials[1 * nblk + blk] = a1;
            partials[2 * nblk + blk] = a2;
            partials[3 * nblk + blk] = a3;
            partials[4 * nblk + blk] = a4;
        }
    }
}

// Epilogue kernel: coalesced single-pass reduction of [5][nblk] partials.
// 256 threads (4 waves) — more loads in flight than a 1-wave version
// (R11 measured the 64-thread variant 2us slower).
__global__ __launch_bounds__(256) void k_final(const float* __restrict__ partials,
                                               float* __restrict__ out, int nblk) {
    __shared__ float wred[4][5];
    const int t = threadIdx.x;
    float s0 = 0.f, s1 = 0.f, s2 = 0.f, s3 = 0.f, s4 = 0.f;
    for (int idx = t; idx < nblk; idx += 256) {
        s0 += partials[0 * nblk + idx];
        s1 += partials[1 * nblk + idx];
        s2 += partials[2 * nblk + idx];
        s3 += partials[3 * nblk + idx];
        s4 += partials[4 * nblk + idx];
    }
    #pragma unroll
    for (int off = 32; off; off >>= 1) {
        s0 += __shfl_xor(s0, off); s1 += __shfl_xor(s1, off);
        s2 += __shfl_xor(s2, off); s3 += __shfl_xor(s3, off);
        s4 += __shfl_xor(s4, off);
    }
    const int wv = t >> 6;
    if ((t & 63) == 0) {
        wred[wv][0] = s0; wred[wv][1] = s1; wred[wv][2] = s2;
        wred[wv][3] = s3; wred[wv][4] = s4;
    }
    __syncthreads();
    if (t == 0) {
        float ce_sum = wred[0][0] + wred[1][0] + wred[2][0] + wred[3][0];
        float vcnt   = wred[0][1] + wred[1][1] + wred[2][1] + wred[3][1];
        float r2_sum = wred[0][2] + wred[1][2] + wred[2][2] + wred[3][2];
        float tvs    = wred[0][3] + wred[1][3] + wred[2][3] + wred[3][3];
        float evo_s  = wred[0][4] + wred[1][4] + wred[2][4] + wred[3][4];
        float ce_loss = (vcnt > 0.f) ? (ce_sum / fmaxf(vcnt, 1.f)) : ce_sum;
        float r2_loss = 0.1f * ((tvs > 0.f) ? (r2_sum / fmaxf(tvs, 1.f)) : r2_sum);
        float evo = 10.f * (evo_s / 32.f);
        if (!isfinite(evo)) evo = 0.f;
        out[0] = 1000.f * (ce_loss + r2_loss + evo);
    }
}

extern "C" void kernel_launch(void* const* d_in, const int* in_sizes, int n_in,
                              void* d_out, int out_size, void* d_ws, size_t ws_size,
                              hipStream_t stream) {
    const float* logits = (const float*)d_in[0];
    const float* prob   = (const float*)d_in[1];
    const float* y_true = (const float*)d_in[2];
    const float* yevo   = (const float*)d_in[3];
    float* out = (float*)d_out;

    const int L = in_sizes[0] / (B * C);   // 4096
    const int nblk = L / WPB;              // 512

    float* partials = (float*)d_ws;        // 5 * nblk floats

    k_main<<<nblk, NTHR, 0, stream>>>(logits, prob, y_true, yevo,
                                      partials, L, nblk);
    k_final<<<1, 256, 0, stream>>>(partials, out, nblk);
}